// Round 13
// baseline (182.221 us; speedup 1.0000x reference)
//
#include <hip/hip_runtime.h>
#include <math.h>

#define B_SZ 32
#define N_NODES 4096
#define C_DIM 64
#define M_EDGES 64
#define DEG 256
#define E_INC 16384
#define NEG_SLOPE 0.2f
#define MARGIN 4.2f

__device__ __forceinline__ float wsum64(float v) {
#pragma unroll
  for (int off = 32; off > 0; off >>= 1) v += __shfl_xor(v, off, 64);
  return v;
}

__device__ __forceinline__ float4 redq16_32(float4 a) {
#pragma unroll
  for (int off = 16; off < 64; off <<= 1) {
    a.x += __shfl_xor(a.x, off, 64);
    a.y += __shfl_xor(a.y, off, 64);
    a.z += __shfl_xor(a.z, off, 64);
    a.w += __shfl_xor(a.w, off, 64);
  }
  return a;
}

#define ACC4(acc, v) \
  acc.x += v.x;      \
  acc.y += v.y;      \
  acc.z += v.z;      \
  acc.w += v.w;

union U16K {
  float wl[4096];
  int cnt[4096];
};

// Phase A: bid<512 s1 streaming pass; bid<576 per-edge counts;
//          bid>=576 es gather (fp32, b-quad, pipelined pair loads).
__global__ __launch_bounds__(256) void k_pA(
    const float* __restrict__ x, const float* __restrict__ w,
    const float* __restrict__ att, const int* __restrict__ node_ids,
    float* __restrict__ s1_t, float* __restrict__ es_t,
    float* __restrict__ s2, float* __restrict__ nrm2,
    float* __restrict__ essum, int* __restrict__ cntv) {
  __shared__ U16K u;
  __shared__ float sx[4][4][64];
  __shared__ float est[4][64];
  const int bid = blockIdx.x;
  const int t = threadIdx.x;
  const int lane = t & 63, wv = t >> 6;
  if (bid < 512) {
    __shared__ float part[4][64];
    __shared__ float wattl[64];
    const int kk = t & 63, q = t >> 6;
    float p = 0.f;
#pragma unroll
    for (int c = 0; c < 16; ++c)
      p = fmaf(w[kk * 64 + q * 16 + c], att[q * 16 + c], p);
    part[q][kk] = p;
    __syncthreads();
    if (t < 64)
      wattl[t] = part[0][t] + part[1][t] + part[2][t] + part[3][t];
    __syncthreads();
    const int kq = lane & 15, rsub = lane >> 4;
    const float4 wq = ((const float4*)wattl)[kq];
    const int r0 = bid * 256 + wv * 64;
#pragma unroll 4
    for (int it = 0; it < 16; ++it) {
      const int row = r0 + it * 4 + rsub;
      const float4 xv = ((const float4*)x)[row * 16 + kq];
      float vv = xv.x * wq.x + xv.y * wq.y + xv.z * wq.z + xv.w * wq.w;
      vv += __shfl_xor(vv, 1, 64);
      vv += __shfl_xor(vv, 2, 64);
      vv += __shfl_xor(vv, 4, 64);
      vv += __shfl_xor(vv, 8, 64);
      if (kq == 0) {
        const int n = row & (N_NODES - 1);
        const int b = row >> 12;
        s1_t[n * 32 + b] = vv;
      }
    }
  } else if (bid < 576) {
    const int m = bid - 512;
#pragma unroll
    for (int i = 0; i < 16; ++i) u.cnt[t + 256 * i] = 0;
    __syncthreads();
    atomicAdd(&u.cnt[node_ids[m * DEG + t]], 1);
    __syncthreads();
#pragma unroll
    for (int i = 0; i < 16; ++i)
      cntv[m * N_NODES + t + 256 * i] = u.cnt[t + 256 * i];
  } else {
    const int eb = bid - 576;
    const int b0 = (eb & 7) * 4;
    const int m = eb >> 3;
    const int qc = lane & 15, rg = lane >> 4;
    float4* wl4 = (float4*)u.wl;
    const float4* w4 = (const float4*)w;
#pragma unroll
    for (int i = 0; i < 4; ++i) wl4[t + 256 * i] = w4[t + 256 * i];
    const int myinc = node_ids[m * DEG + wv * 64 + lane];
    int nds[16];
#pragma unroll
    for (int i = 0; i < 16; ++i) nds[i] = __shfl(myinc, i * 4 + rg, 64);
#pragma unroll
    for (int p = 0; p < 2; ++p) {
      const float4* xA =
          (const float4*)(x + (size_t)(b0 + 2 * p) * (N_NODES * C_DIM));
      const float4* xB =
          (const float4*)(x + (size_t)(b0 + 2 * p + 1) * (N_NODES * C_DIM));
      float4 vA[8], vB[8];
#pragma unroll
      for (int j = 0; j < 8; ++j) vA[j] = xA[nds[j] * 16 + qc];
#pragma unroll
      for (int j = 0; j < 8; ++j) vB[j] = xB[nds[j] * 16 + qc];
      float4 aA = {0.f, 0.f, 0.f, 0.f}, aB = {0.f, 0.f, 0.f, 0.f};
#pragma unroll
      for (int j = 0; j < 8; ++j) { ACC4(aA, vA[j]); }
#pragma unroll
      for (int j = 0; j < 8; ++j) vA[j] = xA[nds[8 + j] * 16 + qc];
#pragma unroll
      for (int j = 0; j < 8; ++j) { ACC4(aB, vB[j]); }
#pragma unroll
      for (int j = 0; j < 8; ++j) vB[j] = xB[nds[8 + j] * 16 + qc];
#pragma unroll
      for (int j = 0; j < 8; ++j) { ACC4(aA, vA[j]); }
#pragma unroll
      for (int j = 0; j < 8; ++j) { ACC4(aB, vB[j]); }
      aA = redq16_32(aA);
      aB = redq16_32(aB);
      if (rg == 0) {
        ((float4*)&sx[wv][2 * p][0])[qc] = aA;
        ((float4*)&sx[wv][2 * p + 1][0])[qc] = aB;
      }
    }
    __syncthreads();
    {
      const int c = lane;
      float es = 0.f;
#pragma unroll 8
      for (int j = 0; j < 64; ++j) {
        const float sxcj =
            sx[0][wv][j] + sx[1][wv][j] + sx[2][wv][j] + sx[3][wv][j];
        es = fmaf(sxcj, u.wl[j * 64 + c], es);
      }
      est[wv][c] = es;
      const float sr = wsum64(es * att[64 + c]);
      const float nr = wsum64(es * es);
      const float er = wsum64(es);
      if (c == 0) {
        s2[m * 32 + b0 + wv] = sr;
        nrm2[m * 32 + b0 + wv] = nr;
        essum[m * 32 + b0 + wv] = er;
      }
    }
    __syncthreads();
    if (t < 64) {
      const float4 o = make_float4(est[0][t], est[1][t], est[2][t], est[3][t]);
      *(float4*)&es_t[(m * 64 + t) * 32 + b0] = o;
    }
  }
}

// Phase B: bid<504 upper-triangle pairwise loss; else branch-free per-(n,b)
// online softmax + packed node->edge lists.
__global__ __launch_bounds__(256) void k_pB(
    const float* __restrict__ es_t, const float* __restrict__ nrm2,
    const int* __restrict__ cntv, const float* __restrict__ s1_t,
    const float* __restrict__ s2, float* __restrict__ lossbuf2,
    float2* __restrict__ pnb, int* __restrict__ pdat,
    int* __restrict__ plen) {
  const int bid = blockIdx.x;
  if (bid < 504) {
    const int wv = threadIdx.x >> 6;
    const int p = bid * 4 + wv;
    int k = 0, off = 0;
    while (off + (63 - k) <= p) {
      off += 63 - k;
      ++k;
    }
    const int m = k + 1 + (p - off);
    const int lane = threadIdx.x & 63;
    const int b = lane & 31, ch = lane >> 5;
    float inner = 0.f;
#pragma unroll 8
    for (int cc = 0; cc < 32; ++cc) {
      const int c = cc + 32 * ch;
      inner = fmaf(es_t[(k * 64 + c) * 32 + b], es_t[(m * 64 + c) * 32 + b],
                   inner);
    }
    inner += __shfl_xor(inner, 32, 64);
    const float nk2 = nrm2[k * 32 + b];
    const float nm2 = nrm2[m * 32 + b];
    const float d2 = fmaxf(nk2 + nm2 - 2.f * inner, 0.f);
    const float dist = sqrtf(d2);
    const float cosv = inner / sqrtf(nk2 * nm2);
    float li = cosv * dist + (1.f - cosv) * fmaxf(MARGIN - dist, 0.f);
#pragma unroll
    for (int o = 16; o > 0; o >>= 1) li += __shfl_xor(li, o, 64);
    if (lane == 0) lossbuf2[p] = 2.f * fabsf(li * (1.f / 32.f));
  } else {
    const int idx = (bid - 504) * 256 + threadIdx.x;
    const int n = idx >> 5, b = idx & 31;
    const float s1v = s1_t[n * 32 + b];
    const bool leader = (b == 0);
    float mx = -1e30f, S = 0.f;
    int j = 0, Dsum = 0;
#pragma unroll 4
    for (int m = 0; m < 64; ++m) {
      const int cm = cntv[m * N_NODES + n];
      float sc = s1v + s2[m * 32 + b];
      sc = sc > 0.f ? sc : NEG_SLOPE * sc;
      const float scv = (cm > 0) ? sc : -1e30f;
      const float nm = fmaxf(mx, scv);
      S = S * __expf(mx - nm) + (float)cm * __expf(scv - nm);
      mx = nm;
      if (leader) {
        if (cm > 0) {
          pdat[n * 64 + j] = m | (cm << 8);
          ++j;
        }
        Dsum += cm;
      }
    }
    if (leader) plen[n] = j | (Dsum << 7);
    float2 pv;
    pv.x = mx;
    pv.y = (S > 0.f) ? 1.f / S : 0.f;
    pnb[n * 32 + b] = pv;
  }
}

// Phase C1: node-major alpha-weighted accumulation into per-wave LDS T[m][k].
// Block = (chunk of 256 nodes) x (b). Writes partialT[ch][b][m][k].
// bid==512: final scalar.
__global__ __launch_bounds__(256) void k_pC1(
    const float* __restrict__ x, const float* __restrict__ s1_t,
    const float* __restrict__ s2, const float2* __restrict__ pnb,
    const int* __restrict__ plen, const int* __restrict__ pdat,
    const float* __restrict__ essum, const float* __restrict__ lossbuf2,
    float* __restrict__ partialT, float* __restrict__ outs) {
  const int bid = blockIdx.x;
  const int t = threadIdx.x;
  if (bid < 512) {
    __shared__ float Tw[4][64][64];  // 64KB: [wave][m][k]
    const int b = bid & 31;
    const int ch = bid >> 5;
    const int c = t & 63, wv = t >> 6;
    float* tz = &Tw[0][0][0];
    for (int i = t; i < 4 * 64 * 64; i += 256) tz[i] = 0.f;
    __syncthreads();
    const int nbase = ch * 256 + wv * 64;
    const float* xb = x + (size_t)b * (N_NODES * C_DIM);
#pragma unroll 1
    for (int g = 0; g < 16; ++g) {
      const int n0 = nbase + g * 4;
      float xv[4], s1v[4];
      int pl[4];
      float2 pv[4];
      int4 pd0[4], pd1[4];
#pragma unroll
      for (int u = 0; u < 4; ++u) {
        const int n = n0 + u;
        xv[u] = xb[n * 64 + c];
        pl[u] = plen[n];
        s1v[u] = s1_t[n * 32 + b];
        pv[u] = pnb[n * 32 + b];
        pd0[u] = *(const int4*)&pdat[n * 64];
        pd1[u] = *(const int4*)&pdat[n * 64 + 4];
      }
#pragma unroll
      for (int u = 0; u < 4; ++u) {
        const int len = pl[u] & 127;
        const int pes[8] = {pd0[u].x, pd0[u].y, pd0[u].z, pd0[u].w,
                            pd1[u].x, pd1[u].y, pd1[u].z, pd1[u].w};
#pragma unroll
        for (int j = 0; j < 8; ++j) {
          if (j < len) {
            const int pe = pes[j];
            const int m = pe & 63;
            float sc = s1v[u] + s2[m * 32 + b];
            sc = sc > 0.f ? sc : NEG_SLOPE * sc;
            const float a =
                (float)(pe >> 8) * __expf(sc - pv[u].x) * pv[u].y;
            Tw[wv][m][c] += a * xv[u];
          }
        }
        for (int j = 8; j < len; ++j) {  // rare tail (len>8)
          const int pe = pdat[(n0 + u) * 64 + j];
          const int m = pe & 63;
          float sc = s1v[u] + s2[m * 32 + b];
          sc = sc > 0.f ? sc : NEG_SLOPE * sc;
          const float a = (float)(pe >> 8) * __expf(sc - pv[u].x) * pv[u].y;
          Tw[wv][m][c] += a * xv[u];
        }
      }
    }
    __syncthreads();
    for (int idx = t; idx < 4096; idx += 256) {
      const int m = idx >> 6, k = idx & 63;
      const float v = Tw[0][m][k] + Tw[1][m][k] + Tw[2][m][k] + Tw[3][m][k];
      partialT[(((size_t)ch * 32 + b) * 64 + m) * 64 + k] = v;
    }
  } else {
    __shared__ float smf[256];
    float s = 0.f;
    for (int i = t; i < M_EDGES * B_SZ; i += 256) s += essum[i];
    smf[t] = s;
    __syncthreads();
    for (int o = 128; o > 0; o >>= 1) {
      if (t < o) smf[t] += smf[t + o];
      __syncthreads();
    }
    const float S = smf[0];
    __syncthreads();
    float l = 0.f;
    for (int i = t; i < 2016; i += 256) l += lossbuf2[i];
    smf[t] = l;
    __syncthreads();
    for (int o = 128; o > 0; o >>= 1) {
      if (t < o) smf[t] += smf[t + o];
      __syncthreads();
    }
    if (t == 0) {
      const float mean = S * (-255.0f) / 33554432.0f;  // sum(x_i-x_j)=-255*S
      outs[0] = fabsf(mean) + smf[0] * (1.0f / 4225.0f);
    }
  }
}

// Phase C2: one block per m. Reduce 16 chunk-partials -> S[k][b], apply @W,
// write out_e_t[m,c,b] = S@W / 256.
__global__ __launch_bounds__(256) void k_pC2(
    const float* __restrict__ partialT, const float* __restrict__ w,
    float* __restrict__ out_e_t) {
  __shared__ float wl[4096];
  __shared__ float S[64][33];  // [k][b] padded
  const int m = blockIdx.x;
  const int t = threadIdx.x;
  float4* wl4 = (float4*)wl;
  const float4* w4 = (const float4*)w;
#pragma unroll
  for (int i = 0; i < 4; ++i) wl4[t + 256 * i] = w4[t + 256 * i];
  const int k = t & 63, bg = t >> 6;  // bg in 0..3
#pragma unroll
  for (int pp = 0; pp < 8; ++pp) {
    const int b = pp * 4 + bg;
    float acc = 0.f;
#pragma unroll
    for (int ch = 0; ch < 16; ++ch)
      acc += partialT[(((size_t)ch * 32 + b) * 64 + m) * 64 + k];
    S[k][b] = acc;
  }
  __syncthreads();
  const int c = t & 63, bq = t >> 6;
#pragma unroll
  for (int j = 0; j < 8; ++j) {
    const int b = bq * 8 + j;
    float oc = 0.f;
#pragma unroll 8
    for (int kk = 0; kk < 64; ++kk) oc = fmaf(S[kk][b], wl[kk * 64 + c], oc);
    out_e_t[(m * 64 + c) * 32 + b] = oc * (1.0f / 256.0f);
  }
}

// Phase D: 2 nodes per block; packed edge list; alpha in LDS.
__global__ __launch_bounds__(256) void k_pD(
    const int* __restrict__ plen, const int* __restrict__ pdat,
    const float* __restrict__ s1_t, const float* __restrict__ s2,
    const float2* __restrict__ pnb, const float* __restrict__ out_e_t,
    float* __restrict__ out) {
  __shared__ int lme[2][64];
  __shared__ float lcnt[2][64];
  __shared__ float al[2][64][32];
  const int t = threadIdx.x;
  const int nd = t >> 7;
  const int n = blockIdx.x * 2 + nd;
  const int tl = t & 127;
  const int pl = plen[n];
  const int len = pl & 127;
  const float Dn = (float)(pl >> 7);
  if (tl < len) {
    const int pe = pdat[n * 64 + tl];
    lme[nd][tl] = pe & 63;
    lcnt[nd][tl] = (float)(pe >> 8);
  }
  __syncthreads();
  {
    const int b = tl & 31, lq = tl >> 5;
    const float s1v = s1_t[n * 32 + b];
    const float2 pv = pnb[n * 32 + b];
    for (int base = 0; base < len; base += 4) {
      const int li = base + lq;
      if (li < len) {
        const int m = lme[nd][li];
        float sc = s1v + s2[m * 32 + b];
        sc = sc > 0.f ? sc : NEG_SLOPE * sc;
        al[nd][li][b] = lcnt[nd][li] * __expf(sc - pv.x) * pv.y;
      }
    }
  }
  __syncthreads();
  const int c = tl & 63, bh = tl >> 6;
  float4 a0 = {0.f, 0.f, 0.f, 0.f}, a1 = {0.f, 0.f, 0.f, 0.f};
  float4 a2 = {0.f, 0.f, 0.f, 0.f}, a3 = {0.f, 0.f, 0.f, 0.f};
  for (int li = 0; li < len; ++li) {
    const int m = lme[nd][li];
    const float* ob = &out_e_t[(m * 64 + c) * 32 + bh * 16];
    const float4 v0 = *(const float4*)(ob);
    const float4 v1 = *(const float4*)(ob + 4);
    const float4 v2 = *(const float4*)(ob + 8);
    const float4 v3 = *(const float4*)(ob + 12);
    const float* alr = &al[nd][li][bh * 16];
    a0.x = fmaf(alr[0], v0.x, a0.x);
    a0.y = fmaf(alr[1], v0.y, a0.y);
    a0.z = fmaf(alr[2], v0.z, a0.z);
    a0.w = fmaf(alr[3], v0.w, a0.w);
    a1.x = fmaf(alr[4], v1.x, a1.x);
    a1.y = fmaf(alr[5], v1.y, a1.y);
    a1.z = fmaf(alr[6], v1.z, a1.z);
    a1.w = fmaf(alr[7], v1.w, a1.w);
    a2.x = fmaf(alr[8], v2.x, a2.x);
    a2.y = fmaf(alr[9], v2.y, a2.y);
    a2.z = fmaf(alr[10], v2.z, a2.z);
    a2.w = fmaf(alr[11], v2.w, a2.w);
    a3.x = fmaf(alr[12], v3.x, a3.x);
    a3.y = fmaf(alr[13], v3.y, a3.y);
    a3.z = fmaf(alr[14], v3.z, a3.z);
    a3.w = fmaf(alr[15], v3.w, a3.w);
  }
  const size_t nb = (size_t)n * 64 + c;
  const size_t st = (size_t)N_NODES * 64;
  const int bb = bh * 16;
  out[(bb + 0) * st + nb] = Dn * a0.x;
  out[(bb + 1) * st + nb] = Dn * a0.y;
  out[(bb + 2) * st + nb] = Dn * a0.z;
  out[(bb + 3) * st + nb] = Dn * a0.w;
  out[(bb + 4) * st + nb] = Dn * a1.x;
  out[(bb + 5) * st + nb] = Dn * a1.y;
  out[(bb + 6) * st + nb] = Dn * a1.z;
  out[(bb + 7) * st + nb] = Dn * a1.w;
  out[(bb + 8) * st + nb] = Dn * a2.x;
  out[(bb + 9) * st + nb] = Dn * a2.y;
  out[(bb + 10) * st + nb] = Dn * a2.z;
  out[(bb + 11) * st + nb] = Dn * a2.w;
  out[(bb + 12) * st + nb] = Dn * a3.x;
  out[(bb + 13) * st + nb] = Dn * a3.y;
  out[(bb + 14) * st + nb] = Dn * a3.z;
  out[(bb + 15) * st + nb] = Dn * a3.w;
}

extern "C" void kernel_launch(void* const* d_in, const int* in_sizes, int n_in,
                              void* d_out, int out_size, void* d_ws,
                              size_t ws_size, hipStream_t stream) {
  (void)in_sizes; (void)n_in; (void)out_size; (void)ws_size;
  const float* x = (const float*)d_in[0];
  const float* weight = (const float*)d_in[1];
  const float* att = (const float*)d_in[2];
  const int* node_ids = (const int*)d_in[3];
  float* out = (float*)d_out;

  char* wsb = (char*)d_ws;
  float* es_t = (float*)(wsb);                     // 512KB [m,c,b]
  float* out_e_t = (float*)(wsb + (512 << 10));    // 512KB [m,c,b]
  float* s1_t = (float*)(wsb + (1024 << 10));      // 512KB [n,b]
  int* cntv = (int*)(wsb + (1536 << 10));          // 1MB   [m,n]
  float2* pnb = (float2*)(wsb + (2560 << 10));     // 1MB   [n,b] {mx,invS}
  int* pdat = (int*)(wsb + (3584 << 10));          // 1MB   [n,64] packed m|cnt
  float* s2 = (float*)(wsb + (4608 << 10));        // 8KB
  float* nrm2 = (float*)(wsb + (4616 << 10));      // 8KB
  float* essum = (float*)(wsb + (4624 << 10));     // 8KB
  float* lossbuf2 = (float*)(wsb + (4632 << 10));  // 8KB (2016 floats)
  int* plen = (int*)(wsb + (4640 << 10));          // 16KB [n] len|Dsum<<7
  float* partialT = (float*)(wsb + (6144 << 10));  // 8MB [ch][b][m][k]

  k_pA<<<1088, 256, 0, stream>>>(x, weight, att, node_ids, s1_t, es_t, s2,
                                 nrm2, essum, cntv);
  k_pB<<<1016, 256, 0, stream>>>(es_t, nrm2, cntv, s1_t, s2, lossbuf2, pnb,
                                 pdat, plen);
  k_pC1<<<513, 256, 0, stream>>>(x, s1_t, s2, pnb, plen, pdat, essum,
                                 lossbuf2, partialT,
                                 out + (size_t)B_SZ * N_NODES * C_DIM);
  k_pC2<<<64, 256, 0, stream>>>(partialT, weight, out_e_t);
  k_pD<<<2048, 256, 0, stream>>>(plen, pdat, s1_t, s2, pnb, out_e_t, out);
}

// Round 14
// 84.948 us; speedup vs baseline: 2.1451x; 2.1451x over previous
//
#include <hip/hip_runtime.h>
#include <math.h>

#define B_SZ 32
#define N_NODES 4096
#define C_DIM 64
#define M_EDGES 64
#define DEG 256
#define E_INC 16384
#define NEG_SLOPE 0.2f
#define MARGIN 4.2f

__device__ __forceinline__ float wsum64(float v) {
#pragma unroll
  for (int off = 32; off > 0; off >>= 1) v += __shfl_xor(v, off, 64);
  return v;
}

__device__ __forceinline__ float4 redq16_32(float4 a) {
#pragma unroll
  for (int off = 16; off < 64; off <<= 1) {
    a.x += __shfl_xor(a.x, off, 64);
    a.y += __shfl_xor(a.y, off, 64);
    a.z += __shfl_xor(a.z, off, 64);
    a.w += __shfl_xor(a.w, off, 64);
  }
  return a;
}

#define ACC4(acc, v) \
  acc.x += v.x;      \
  acc.y += v.y;      \
  acc.z += v.z;      \
  acc.w += v.w;

#define FMA4(acc, a, v)        \
  acc.x = fmaf(a, v.x, acc.x); \
  acc.y = fmaf(a, v.y, acc.y); \
  acc.z = fmaf(a, v.z, acc.z); \
  acc.w = fmaf(a, v.w, acc.w);

union U16K {
  float wl[4096];
  int cnt[4096];
};

// Phase A: bid<512 s1 streaming pass; bid<576 per-edge counts;
//          bid>=576 es gather: wave-per-panel (ids staged in LDS).
__global__ __launch_bounds__(256) void k_pA(
    const float* __restrict__ x, const float* __restrict__ w,
    const float* __restrict__ att, const int* __restrict__ node_ids,
    float* __restrict__ s1_t, float* __restrict__ es_t,
    float* __restrict__ s2, float* __restrict__ nrm2,
    float* __restrict__ essum, int* __restrict__ cntv) {
  __shared__ U16K u;
  __shared__ int ids[256];
  __shared__ float sxc[4][64];
  __shared__ float est[4][64];
  const int bid = blockIdx.x;
  const int t = threadIdx.x;
  const int lane = t & 63, wv = t >> 6;
  if (bid < 512) {
    __shared__ float part[4][64];
    __shared__ float wattl[64];
    const int kk = t & 63, q = t >> 6;
    float p = 0.f;
#pragma unroll
    for (int c = 0; c < 16; ++c)
      p = fmaf(w[kk * 64 + q * 16 + c], att[q * 16 + c], p);
    part[q][kk] = p;
    __syncthreads();
    if (t < 64)
      wattl[t] = part[0][t] + part[1][t] + part[2][t] + part[3][t];
    __syncthreads();
    const int kq = lane & 15, rsub = lane >> 4;
    const float4 wq = ((const float4*)wattl)[kq];
    const int r0 = bid * 256 + wv * 64;
#pragma unroll 4
    for (int it = 0; it < 16; ++it) {
      const int row = r0 + it * 4 + rsub;
      const float4 xv = ((const float4*)x)[row * 16 + kq];
      float vv = xv.x * wq.x + xv.y * wq.y + xv.z * wq.z + xv.w * wq.w;
      vv += __shfl_xor(vv, 1, 64);
      vv += __shfl_xor(vv, 2, 64);
      vv += __shfl_xor(vv, 4, 64);
      vv += __shfl_xor(vv, 8, 64);
      if (kq == 0) {
        const int n = row & (N_NODES - 1);
        const int b = row >> 12;
        s1_t[n * 32 + b] = vv;
      }
    }
  } else if (bid < 576) {
    const int m = bid - 512;
#pragma unroll
    for (int i = 0; i < 16; ++i) u.cnt[t + 256 * i] = 0;
    __syncthreads();
    atomicAdd(&u.cnt[node_ids[m * DEG + t]], 1);
    __syncthreads();
#pragma unroll
    for (int i = 0; i < 16; ++i)
      cntv[m * N_NODES + t + 256 * i] = u.cnt[t + 256 * i];
  } else {
    // ---- es gather: block = (m, b-quad); wave wv owns panel b0+wv fully.
    const int eb = bid - 576;
    const int b0 = (eb & 7) * 4;
    const int m = eb >> 3;
    const int qc = lane & 15, rg = lane >> 4;
    ids[t] = node_ids[m * DEG + t];
    float4* wl4 = (float4*)u.wl;
    const float4* w4 = (const float4*)w;
#pragma unroll
    for (int i = 0; i < 4; ++i) wl4[t + 256 * i] = w4[t + 256 * i];
    __syncthreads();
    const int b = b0 + wv;
    const float4* xb4 = (const float4*)(x + (size_t)b * (N_NODES * C_DIM));
    float4 acc = {0.f, 0.f, 0.f, 0.f};
#pragma unroll
    for (int h = 0; h < 8; ++h) {
      int nd[8];
      float4 v[8];
#pragma unroll
      for (int j = 0; j < 8; ++j) nd[j] = ids[(h * 8 + j) * 4 + rg];
#pragma unroll
      for (int j = 0; j < 8; ++j) v[j] = xb4[nd[j] * 16 + qc];
#pragma unroll
      for (int j = 0; j < 8; ++j) { ACC4(acc, v[j]); }
    }
    acc = redq16_32(acc);
    if (rg == 0) ((float4*)&sxc[wv][0])[qc] = acc;
    __syncthreads();
    {
      const int c = lane;
      float es = 0.f;
#pragma unroll 8
      for (int j = 0; j < 64; ++j) es = fmaf(sxc[wv][j], u.wl[j * 64 + c], es);
      est[wv][c] = es;
      const float sr = wsum64(es * att[64 + c]);
      const float nr = wsum64(es * es);
      const float er = wsum64(es);
      if (c == 0) {
        s2[m * 32 + b] = sr;
        nrm2[m * 32 + b] = nr;
        essum[m * 32 + b] = er;
      }
    }
    __syncthreads();
    if (t < 64) {
      const float4 o = make_float4(est[0][t], est[1][t], est[2][t], est[3][t]);
      *(float4*)&es_t[(m * 64 + t) * 32 + b0] = o;
    }
  }
}

// Phase B: bid<504 upper-triangle pairwise loss; else branch-free per-(n,b)
// online softmax + packed node->edge lists.
__global__ __launch_bounds__(256) void k_pB(
    const float* __restrict__ es_t, const float* __restrict__ nrm2,
    const int* __restrict__ cntv, const float* __restrict__ s1_t,
    const float* __restrict__ s2, float* __restrict__ lossbuf2,
    float2* __restrict__ pnb, int* __restrict__ pdat,
    int* __restrict__ plen) {
  const int bid = blockIdx.x;
  if (bid < 504) {
    const int wv = threadIdx.x >> 6;
    const int p = bid * 4 + wv;
    int k = 0, off = 0;
    while (off + (63 - k) <= p) {
      off += 63 - k;
      ++k;
    }
    const int m = k + 1 + (p - off);
    const int lane = threadIdx.x & 63;
    const int b = lane & 31, ch = lane >> 5;
    float inner = 0.f;
#pragma unroll 8
    for (int cc = 0; cc < 32; ++cc) {
      const int c = cc + 32 * ch;
      inner = fmaf(es_t[(k * 64 + c) * 32 + b], es_t[(m * 64 + c) * 32 + b],
                   inner);
    }
    inner += __shfl_xor(inner, 32, 64);
    const float nk2 = nrm2[k * 32 + b];
    const float nm2 = nrm2[m * 32 + b];
    const float d2 = fmaxf(nk2 + nm2 - 2.f * inner, 0.f);
    const float dist = sqrtf(d2);
    const float cosv = inner / sqrtf(nk2 * nm2);
    float li = cosv * dist + (1.f - cosv) * fmaxf(MARGIN - dist, 0.f);
#pragma unroll
    for (int o = 16; o > 0; o >>= 1) li += __shfl_xor(li, o, 64);
    if (lane == 0) lossbuf2[p] = 2.f * fabsf(li * (1.f / 32.f));
  } else {
    const int idx = (bid - 504) * 256 + threadIdx.x;
    const int n = idx >> 5, b = idx & 31;
    const float s1v = s1_t[n * 32 + b];
    const bool leader = (b == 0);
    float mx = -1e30f, S = 0.f;
    int j = 0, Dsum = 0;
#pragma unroll 4
    for (int m = 0; m < 64; ++m) {
      const int cm = cntv[m * N_NODES + n];
      float sc = s1v + s2[m * 32 + b];
      sc = sc > 0.f ? sc : NEG_SLOPE * sc;
      const float scv = (cm > 0) ? sc : -1e30f;
      const float nm = fmaxf(mx, scv);
      S = S * __expf(mx - nm) + (float)cm * __expf(scv - nm);
      mx = nm;
      if (leader) {
        if (cm > 0) {
          pdat[n * 64 + j] = m | (cm << 8);
          ++j;
        }
        Dsum += cm;
      }
    }
    if (leader) plen[n] = j | (Dsum << 7);
    float2 pv;
    pv.x = mx;
    pv.y = (S > 0.f) ? 1.f / S : 0.f;
    pnb[n * 32 + b] = pv;
  }
}

// Phase C: bid<512 alpha-weighted gather, wave-per-panel; bid==512 scalar.
__global__ __launch_bounds__(256) void k_pC(
    const float* __restrict__ x, const int* __restrict__ node_ids,
    const float* __restrict__ w, const float* __restrict__ s1_t,
    const float* __restrict__ s2, const float2* __restrict__ pnb,
    const float* __restrict__ essum, const float* __restrict__ lossbuf2,
    float* __restrict__ out_e_t, float* __restrict__ outs) {
  __shared__ float wl[4096];
  __shared__ int ids[256];
  __shared__ float al[4][256];
  __shared__ float sxc[4][64];
  __shared__ float est[4][64];
  const int bid = blockIdx.x;
  const int t = threadIdx.x;
  if (bid < 512) {
    const int b0 = (bid & 7) * 4;
    const int m = bid >> 3;
    const int lane = t & 63, wv = t >> 6;
    const int qc = lane & 15, rg = lane >> 4;
    ids[t] = node_ids[m * DEG + t];
    float4* wl4 = (float4*)wl;
    const float4* w4 = (const float4*)w;
#pragma unroll
    for (int i = 0; i < 4; ++i) wl4[t + 256 * i] = w4[t + 256 * i];
    __syncthreads();
    const int b = b0 + wv;
    const float s2mb = s2[m * 32 + b];
    // each lane computes alpha for 4 incidences at its wave's b
#pragma unroll
    for (int q = 0; q < 4; ++q) {
      const int r = lane * 4 + q;
      const int n = ids[r];
      const float2 pv = pnb[n * 32 + b];
      float sc = s1_t[n * 32 + b] + s2mb;
      sc = sc > 0.f ? sc : NEG_SLOPE * sc;
      al[wv][r] = __expf(sc - pv.x) * pv.y;
    }
    const float4* xb4 = (const float4*)(x + (size_t)b * (N_NODES * C_DIM));
    float4 acc = {0.f, 0.f, 0.f, 0.f};
#pragma unroll
    for (int h = 0; h < 8; ++h) {
      int nd[8];
      float av[8];
      float4 v[8];
#pragma unroll
      for (int j = 0; j < 8; ++j) {
        const int r = (h * 8 + j) * 4 + rg;
        nd[j] = ids[r];
        av[j] = al[wv][r];
      }
#pragma unroll
      for (int j = 0; j < 8; ++j) v[j] = xb4[nd[j] * 16 + qc];
#pragma unroll
      for (int j = 0; j < 8; ++j) { FMA4(acc, av[j], v[j]); }
    }
    acc = redq16_32(acc);
    if (rg == 0) ((float4*)&sxc[wv][0])[qc] = acc;
    __syncthreads();
    {
      const int c = lane;
      float oc = 0.f;
#pragma unroll 8
      for (int j = 0; j < 64; ++j) oc = fmaf(sxc[wv][j], wl[j * 64 + c], oc);
      est[wv][c] = oc * (1.0f / 256.0f);
    }
    __syncthreads();
    if (t < 64) {
      const float4 o = make_float4(est[0][t], est[1][t], est[2][t], est[3][t]);
      *(float4*)&out_e_t[(m * 64 + t) * 32 + b0] = o;
    }
  } else {
    __shared__ float smf[256];
    float s = 0.f;
    for (int i = t; i < M_EDGES * B_SZ; i += 256) s += essum[i];
    smf[t] = s;
    __syncthreads();
    for (int o = 128; o > 0; o >>= 1) {
      if (t < o) smf[t] += smf[t + o];
      __syncthreads();
    }
    const float S = smf[0];
    __syncthreads();
    float l = 0.f;
    for (int i = t; i < 2016; i += 256) l += lossbuf2[i];
    smf[t] = l;
    __syncthreads();
    for (int o = 128; o > 0; o >>= 1) {
      if (t < o) smf[t] += smf[t + o];
      __syncthreads();
    }
    if (t == 0) {
      const float mean = S * (-255.0f) / 33554432.0f;  // sum(x_i-x_j)=-255*S
      outs[0] = fabsf(mean) + smf[0] * (1.0f / 4225.0f);
    }
  }
}

// Phase D: 2 nodes per block; packed edge list; alpha in LDS.
__global__ __launch_bounds__(256) void k_pD(
    const int* __restrict__ plen, const int* __restrict__ pdat,
    const float* __restrict__ s1_t, const float* __restrict__ s2,
    const float2* __restrict__ pnb, const float* __restrict__ out_e_t,
    float* __restrict__ out) {
  __shared__ int lme[2][64];
  __shared__ float lcnt[2][64];
  __shared__ float al[2][64][32];
  const int t = threadIdx.x;
  const int nd = t >> 7;
  const int n = blockIdx.x * 2 + nd;
  const int tl = t & 127;
  const int pl = plen[n];
  const int len = pl & 127;
  const float Dn = (float)(pl >> 7);
  if (tl < len) {
    const int pe = pdat[n * 64 + tl];
    lme[nd][tl] = pe & 63;
    lcnt[nd][tl] = (float)(pe >> 8);
  }
  __syncthreads();
  {
    const int b = tl & 31, lq = tl >> 5;
    const float s1v = s1_t[n * 32 + b];
    const float2 pv = pnb[n * 32 + b];
    for (int base = 0; base < len; base += 4) {
      const int li = base + lq;
      if (li < len) {
        const int m = lme[nd][li];
        float sc = s1v + s2[m * 32 + b];
        sc = sc > 0.f ? sc : NEG_SLOPE * sc;
        al[nd][li][b] = lcnt[nd][li] * __expf(sc - pv.x) * pv.y;
      }
    }
  }
  __syncthreads();
  const int c = tl & 63, bh = tl >> 6;
  float4 a0 = {0.f, 0.f, 0.f, 0.f}, a1 = {0.f, 0.f, 0.f, 0.f};
  float4 a2 = {0.f, 0.f, 0.f, 0.f}, a3 = {0.f, 0.f, 0.f, 0.f};
  for (int li = 0; li < len; ++li) {
    const int m = lme[nd][li];
    const float* ob = &out_e_t[(m * 64 + c) * 32 + bh * 16];
    const float4 v0 = *(const float4*)(ob);
    const float4 v1 = *(const float4*)(ob + 4);
    const float4 v2 = *(const float4*)(ob + 8);
    const float4 v3 = *(const float4*)(ob + 12);
    const float* alr = &al[nd][li][bh * 16];
    a0.x = fmaf(alr[0], v0.x, a0.x);
    a0.y = fmaf(alr[1], v0.y, a0.y);
    a0.z = fmaf(alr[2], v0.z, a0.z);
    a0.w = fmaf(alr[3], v0.w, a0.w);
    a1.x = fmaf(alr[4], v1.x, a1.x);
    a1.y = fmaf(alr[5], v1.y, a1.y);
    a1.z = fmaf(alr[6], v1.z, a1.z);
    a1.w = fmaf(alr[7], v1.w, a1.w);
    a2.x = fmaf(alr[8], v2.x, a2.x);
    a2.y = fmaf(alr[9], v2.y, a2.y);
    a2.z = fmaf(alr[10], v2.z, a2.z);
    a2.w = fmaf(alr[11], v2.w, a2.w);
    a3.x = fmaf(alr[12], v3.x, a3.x);
    a3.y = fmaf(alr[13], v3.y, a3.y);
    a3.z = fmaf(alr[14], v3.z, a3.z);
    a3.w = fmaf(alr[15], v3.w, a3.w);
  }
  const size_t nb = (size_t)n * 64 + c;
  const size_t st = (size_t)N_NODES * 64;
  const int bb = bh * 16;
  out[(bb + 0) * st + nb] = Dn * a0.x;
  out[(bb + 1) * st + nb] = Dn * a0.y;
  out[(bb + 2) * st + nb] = Dn * a0.z;
  out[(bb + 3) * st + nb] = Dn * a0.w;
  out[(bb + 4) * st + nb] = Dn * a1.x;
  out[(bb + 5) * st + nb] = Dn * a1.y;
  out[(bb + 6) * st + nb] = Dn * a1.z;
  out[(bb + 7) * st + nb] = Dn * a1.w;
  out[(bb + 8) * st + nb] = Dn * a2.x;
  out[(bb + 9) * st + nb] = Dn * a2.y;
  out[(bb + 10) * st + nb] = Dn * a2.z;
  out[(bb + 11) * st + nb] = Dn * a2.w;
  out[(bb + 12) * st + nb] = Dn * a3.x;
  out[(bb + 13) * st + nb] = Dn * a3.y;
  out[(bb + 14) * st + nb] = Dn * a3.z;
  out[(bb + 15) * st + nb] = Dn * a3.w;
}

extern "C" void kernel_launch(void* const* d_in, const int* in_sizes, int n_in,
                              void* d_out, int out_size, void* d_ws,
                              size_t ws_size, hipStream_t stream) {
  (void)in_sizes; (void)n_in; (void)out_size; (void)ws_size;
  const float* x = (const float*)d_in[0];
  const float* weight = (const float*)d_in[1];
  const float* att = (const float*)d_in[2];
  const int* node_ids = (const int*)d_in[3];
  float* out = (float*)d_out;

  char* wsb = (char*)d_ws;
  float* es_t = (float*)(wsb);                     // 512KB [m,c,b]
  float* out_e_t = (float*)(wsb + (512 << 10));    // 512KB [m,c,b]
  float* s1_t = (float*)(wsb + (1024 << 10));      // 512KB [n,b]
  int* cntv = (int*)(wsb + (1536 << 10));          // 1MB   [m,n]
  float2* pnb = (float2*)(wsb + (2560 << 10));     // 1MB   [n,b] {mx,invS}
  int* pdat = (int*)(wsb + (3584 << 10));          // 1MB   [n,64] packed m|cnt
  float* s2 = (float*)(wsb + (4608 << 10));        // 8KB
  float* nrm2 = (float*)(wsb + (4616 << 10));      // 8KB
  float* essum = (float*)(wsb + (4624 << 10));     // 8KB
  float* lossbuf2 = (float*)(wsb + (4632 << 10));  // 8KB (2016 floats)
  int* plen = (int*)(wsb + (4640 << 10));          // 16KB [n] len|Dsum<<7

  k_pA<<<1088, 256, 0, stream>>>(x, weight, att, node_ids, s1_t, es_t, s2,
                                 nrm2, essum, cntv);
  k_pB<<<1016, 256, 0, stream>>>(es_t, nrm2, cntv, s1_t, s2, lossbuf2, pnb,
                                 pdat, plen);
  k_pC<<<513, 256, 0, stream>>>(x, node_ids, weight, s1_t, s2, pnb, essum,
                                lossbuf2, out_e_t,
                                out + (size_t)B_SZ * N_NODES * C_DIM);
  k_pD<<<2048, 256, 0, stream>>>(plen, pdat, s1_t, s2, pnb, out_e_t, out);
}

// Round 15
// 81.089 us; speedup vs baseline: 2.2472x; 1.0476x over previous
//
#include <hip/hip_runtime.h>
#include <math.h>

#define B_SZ 32
#define N_NODES 4096
#define C_DIM 64
#define M_EDGES 64
#define DEG 256
#define E_INC 16384
#define NEG_SLOPE 0.2f
#define MARGIN 4.2f

__device__ __forceinline__ float wsum64(float v) {
#pragma unroll
  for (int off = 32; off > 0; off >>= 1) v += __shfl_xor(v, off, 64);
  return v;
}

__device__ __forceinline__ float4 redq16_32(float4 a) {
#pragma unroll
  for (int off = 16; off < 64; off <<= 1) {
    a.x += __shfl_xor(a.x, off, 64);
    a.y += __shfl_xor(a.y, off, 64);
    a.z += __shfl_xor(a.z, off, 64);
    a.w += __shfl_xor(a.w, off, 64);
  }
  return a;
}

union U16K {
  float wl[4096];
  int cnt[4096];
};

// Phase A: bid<512 s1 streaming pass; bid<576 per-edge counts;
//          bid>=576 es gather (fp32, b-quad, wave-parallel epilogue).
__global__ __launch_bounds__(256) void k_pA(
    const float* __restrict__ x, const float* __restrict__ w,
    const float* __restrict__ att, const int* __restrict__ node_ids,
    float* __restrict__ s1_t, float* __restrict__ es_t,
    float* __restrict__ s2, float* __restrict__ nrm2,
    float* __restrict__ essum, int* __restrict__ cntv) {
  __shared__ U16K u;
  __shared__ float sx[4][4][64];
  __shared__ float est[4][64];
  const int bid = blockIdx.x;
  const int t = threadIdx.x;
  const int lane = t & 63, wv = t >> 6;
  if (bid < 512) {
    // ---- s1 stream: s1_t[n*32+b] = dot(x[b,n,:], W@att0), 256 rows/block
    __shared__ float part[4][64];
    __shared__ float wattl[64];
    const int kk = t & 63, q = t >> 6;
    float p = 0.f;
#pragma unroll
    for (int c = 0; c < 16; ++c)
      p = fmaf(w[kk * 64 + q * 16 + c], att[q * 16 + c], p);
    part[q][kk] = p;
    __syncthreads();
    if (t < 64)
      wattl[t] = part[0][t] + part[1][t] + part[2][t] + part[3][t];
    __syncthreads();
    const int kq = lane & 15, rsub = lane >> 4;
    const float4 wq = ((const float4*)wattl)[kq];
    const int r0 = bid * 256 + wv * 64;
#pragma unroll 4
    for (int it = 0; it < 16; ++it) {
      const int row = r0 + it * 4 + rsub;
      const float4 xv = ((const float4*)x)[row * 16 + kq];
      float vv = xv.x * wq.x + xv.y * wq.y + xv.z * wq.z + xv.w * wq.w;
      vv += __shfl_xor(vv, 1, 64);
      vv += __shfl_xor(vv, 2, 64);
      vv += __shfl_xor(vv, 4, 64);
      vv += __shfl_xor(vv, 8, 64);
      if (kq == 0) {
        const int n = row & (N_NODES - 1);
        const int b = row >> 12;
        s1_t[n * 32 + b] = vv;
      }
    }
  } else if (bid < 576) {
    // ---- per-edge incidence counts (coalesced rows)
    const int m = bid - 512;
#pragma unroll
    for (int i = 0; i < 16; ++i) u.cnt[t + 256 * i] = 0;
    __syncthreads();
    atomicAdd(&u.cnt[node_ids[m * DEG + t]], 1);
    __syncthreads();
#pragma unroll
    for (int i = 0; i < 16; ++i)
      cntv[m * N_NODES + t + 256 * i] = u.cnt[t + 256 * i];
  } else {
    // ---- es gather: block = (m, b-quad)
    const int eb = bid - 576;
    const int b0 = (eb & 7) * 4;
    const int m = eb >> 3;
    const int qc = lane & 15, rg = lane >> 4;
    float4* wl4 = (float4*)u.wl;
    const float4* w4 = (const float4*)w;
#pragma unroll
    for (int i = 0; i < 4; ++i) wl4[t + 256 * i] = w4[t + 256 * i];
    const int myinc = node_ids[m * DEG + wv * 64 + lane];
    int nds[16];
#pragma unroll
    for (int i = 0; i < 16; ++i) nds[i] = __shfl(myinc, i * 4 + rg, 64);
#pragma unroll
    for (int bi = 0; bi < 4; ++bi) {
      const float4* xb4 =
          (const float4*)(x + (size_t)(b0 + bi) * (N_NODES * C_DIM));
      float4 acc = {0.f, 0.f, 0.f, 0.f};
#pragma unroll
      for (int h = 0; h < 2; ++h) {
        float4 v[8];
#pragma unroll
        for (int j = 0; j < 8; ++j) v[j] = xb4[nds[h * 8 + j] * 16 + qc];
#pragma unroll
        for (int j = 0; j < 8; ++j) {
          acc.x += v[j].x;
          acc.y += v[j].y;
          acc.z += v[j].z;
          acc.w += v[j].w;
        }
      }
      acc = redq16_32(acc);
      if (rg == 0) ((float4*)&sx[wv][bi][0])[qc] = acc;
    }
    __syncthreads();
    {
      const int c = lane;
      float es = 0.f;
#pragma unroll 8
      for (int j = 0; j < 64; ++j) {
        const float sxcj =
            sx[0][wv][j] + sx[1][wv][j] + sx[2][wv][j] + sx[3][wv][j];
        es = fmaf(sxcj, u.wl[j * 64 + c], es);
      }
      est[wv][c] = es;
      const float sr = wsum64(es * att[64 + c]);
      const float nr = wsum64(es * es);
      const float er = wsum64(es);
      if (c == 0) {
        s2[m * 32 + b0 + wv] = sr;
        nrm2[m * 32 + b0 + wv] = nr;
        essum[m * 32 + b0 + wv] = er;
      }
    }
    __syncthreads();
    if (t < 64) {
      const float4 o = make_float4(est[0][t], est[1][t], est[2][t], est[3][t]);
      *(float4*)&es_t[(m * 64 + t) * 32 + b0] = o;
    }
  }
}

// Phase B: bid<504 upper-triangle pairwise loss; else branch-free per-(n,b)
// online softmax + packed node->edge lists.
__global__ __launch_bounds__(256) void k_pB(
    const float* __restrict__ es_t, const float* __restrict__ nrm2,
    const int* __restrict__ cntv, const float* __restrict__ s1_t,
    const float* __restrict__ s2, float* __restrict__ lossbuf2,
    float2* __restrict__ pnb, int* __restrict__ pdat,
    int* __restrict__ plen) {
  const int bid = blockIdx.x;
  if (bid < 504) {
    const int wv = threadIdx.x >> 6;
    const int p = bid * 4 + wv;
    int k = 0, off = 0;
    while (off + (63 - k) <= p) {
      off += 63 - k;
      ++k;
    }
    const int m = k + 1 + (p - off);
    const int lane = threadIdx.x & 63;
    const int b = lane & 31, ch = lane >> 5;
    float inner = 0.f;
#pragma unroll 8
    for (int cc = 0; cc < 32; ++cc) {
      const int c = cc + 32 * ch;
      inner = fmaf(es_t[(k * 64 + c) * 32 + b], es_t[(m * 64 + c) * 32 + b],
                   inner);
    }
    inner += __shfl_xor(inner, 32, 64);
    const float nk2 = nrm2[k * 32 + b];
    const float nm2 = nrm2[m * 32 + b];
    const float d2 = fmaxf(nk2 + nm2 - 2.f * inner, 0.f);
    const float dist = sqrtf(d2);
    const float cosv = inner / sqrtf(nk2 * nm2);
    float li = cosv * dist + (1.f - cosv) * fmaxf(MARGIN - dist, 0.f);
#pragma unroll
    for (int o = 16; o > 0; o >>= 1) li += __shfl_xor(li, o, 64);
    if (lane == 0) lossbuf2[p] = 2.f * fabsf(li * (1.f / 32.f));
  } else {
    const int idx = (bid - 504) * 256 + threadIdx.x;
    const int n = idx >> 5, b = idx & 31;
    const float s1v = s1_t[n * 32 + b];
    const bool leader = (b == 0);
    float mx = -1e30f, S = 0.f;
    int j = 0, Dsum = 0;
#pragma unroll 4
    for (int m = 0; m < 64; ++m) {
      const int cm = cntv[m * N_NODES + n];
      float sc = s1v + s2[m * 32 + b];
      sc = sc > 0.f ? sc : NEG_SLOPE * sc;
      const float scv = (cm > 0) ? sc : -1e30f;
      const float nm = fmaxf(mx, scv);
      S = S * __expf(mx - nm) + (float)cm * __expf(scv - nm);
      mx = nm;
      if (leader) {
        if (cm > 0) {
          pdat[n * 64 + j] = m | (cm << 8);
          ++j;
        }
        Dsum += cm;
      }
    }
    if (leader) plen[n] = j | (Dsum << 7);
    float2 pv;
    pv.x = mx;
    pv.y = (S > 0.f) ? 1.f / S : 0.f;
    pnb[n * 32 + b] = pv;
  }
}

// Phase C: bid<512 alpha-weighted gather (fp32, b-quad); bid==512 final scalar.
__global__ __launch_bounds__(256) void k_pC(
    const float* __restrict__ x, const int* __restrict__ node_ids,
    const float* __restrict__ w, const float* __restrict__ s1_t,
    const float* __restrict__ s2, const float2* __restrict__ pnb,
    const float* __restrict__ essum, const float* __restrict__ lossbuf2,
    float* __restrict__ out_e_t, float* __restrict__ outs) {
  __shared__ float wl[4096];
  __shared__ float sx[4][4][64];
  __shared__ float est[4][64];
  const int bid = blockIdx.x;
  const int t = threadIdx.x;
  if (bid < 512) {
    const int b0 = (bid & 7) * 4;
    const int m = bid >> 3;
    const int lane = t & 63, wv = t >> 6;
    const int qc = lane & 15, rg = lane >> 4;
    float4* wl4 = (float4*)wl;
    const float4* w4 = (const float4*)w;
#pragma unroll
    for (int i = 0; i < 4; ++i) wl4[t + 256 * i] = w4[t + 256 * i];
    const int myinc = node_ids[m * DEG + wv * 64 + lane];
    const float4 s14 = *(const float4*)&s1_t[myinc * 32 + b0];
    const float* pp = (const float*)&pnb[myinc * 32 + b0];
    const float4 pA = *(const float4*)pp;
    const float4 pB = *(const float4*)(pp + 4);
    float mya[4];
    {
      const float s1a[4] = {s14.x, s14.y, s14.z, s14.w};
      const float mxa[4] = {pA.x, pA.z, pB.x, pB.z};
      const float iva[4] = {pA.y, pA.w, pB.y, pB.w};
#pragma unroll
      for (int bi = 0; bi < 4; ++bi) {
        float sc = s1a[bi] + s2[m * 32 + b0 + bi];
        sc = sc > 0.f ? sc : NEG_SLOPE * sc;
        mya[bi] = __expf(sc - mxa[bi]) * iva[bi];
      }
    }
    int nds[16];
#pragma unroll
    for (int i = 0; i < 16; ++i) nds[i] = __shfl(myinc, i * 4 + rg, 64);
#pragma unroll
    for (int bi = 0; bi < 4; ++bi) {
      const float4* xb4 =
          (const float4*)(x + (size_t)(b0 + bi) * (N_NODES * C_DIM));
      float4 acc = {0.f, 0.f, 0.f, 0.f};
#pragma unroll
      for (int h = 0; h < 2; ++h) {
        float4 v[8];
        float av[8];
#pragma unroll
        for (int j = 0; j < 8; ++j) {
          av[j] = __shfl(mya[bi], (h * 8 + j) * 4 + rg, 64);
          v[j] = xb4[nds[h * 8 + j] * 16 + qc];
        }
#pragma unroll
        for (int j = 0; j < 8; ++j) {
          acc.x = fmaf(av[j], v[j].x, acc.x);
          acc.y = fmaf(av[j], v[j].y, acc.y);
          acc.z = fmaf(av[j], v[j].z, acc.z);
          acc.w = fmaf(av[j], v[j].w, acc.w);
        }
      }
      acc = redq16_32(acc);
      if (rg == 0) ((float4*)&sx[wv][bi][0])[qc] = acc;
    }
    __syncthreads();
    {
      const int c = t & 63;
      const int wv2 = t >> 6;
      float oc = 0.f;
#pragma unroll 8
      for (int j = 0; j < 64; ++j) {
        const float sxcj =
            sx[0][wv2][j] + sx[1][wv2][j] + sx[2][wv2][j] + sx[3][wv2][j];
        oc = fmaf(sxcj, wl[j * 64 + c], oc);
      }
      est[wv2][c] = oc * (1.0f / 256.0f);
    }
    __syncthreads();
    if (t < 64) {
      const float4 o = make_float4(est[0][t], est[1][t], est[2][t], est[3][t]);
      *(float4*)&out_e_t[(m * 64 + t) * 32 + b0] = o;
    }
  } else {
    __shared__ float smf[256];
    float s = 0.f;
    for (int i = t; i < M_EDGES * B_SZ; i += 256) s += essum[i];
    smf[t] = s;
    __syncthreads();
    for (int o = 128; o > 0; o >>= 1) {
      if (t < o) smf[t] += smf[t + o];
      __syncthreads();
    }
    const float S = smf[0];
    __syncthreads();
    float l = 0.f;
    for (int i = t; i < 2016; i += 256) l += lossbuf2[i];
    smf[t] = l;
    __syncthreads();
    for (int o = 128; o > 0; o >>= 1) {
      if (t < o) smf[t] += smf[t + o];
      __syncthreads();
    }
    if (t == 0) {
      const float mean = S * (-255.0f) / 33554432.0f;  // sum(x_i-x_j)=-255*S
      outs[0] = fabsf(mean) + smf[0] * (1.0f / 4225.0f);
    }
  }
}

// Phase D: per node, packed edge list; alpha in LDS; coalesced header.
__global__ __launch_bounds__(256) void k_pD(
    const int* __restrict__ plen, const int* __restrict__ pdat,
    const float* __restrict__ s1_t, const float* __restrict__ s2,
    const float2* __restrict__ pnb, const float* __restrict__ out_e_t,
    float* __restrict__ out) {
  __shared__ int lme[64];
  __shared__ float lcnt[64];
  __shared__ float al[64][32];
  const int n = blockIdx.x;
  const int t = threadIdx.x;
  const int pl = plen[n];
  const int len = pl & 127;
  const float Dn = (float)(pl >> 7);
  const int c = t & 63, bq = t >> 6;
  const size_t nb = (size_t)n * 64 + c;
  const size_t st = (size_t)N_NODES * 64;
  if (len == 0) {
#pragma unroll
    for (int j = 0; j < 8; ++j) out[(bq * 8 + j) * st + nb] = 0.f;
    return;
  }
  if (t < len) {
    const int pe = pdat[n * 64 + t];
    lme[t] = pe & 63;
    lcnt[t] = (float)(pe >> 8);
  }
  __syncthreads();
  {
    const int b = t & 31, lq = t >> 5;
    const float s1v = s1_t[n * 32 + b];
    const float2 pv = pnb[n * 32 + b];
    for (int base = 0; base < len; base += 8) {
      const int li = base + lq;
      if (li < len) {
        const int m = lme[li];
        float sc = s1v + s2[m * 32 + b];
        sc = sc > 0.f ? sc : NEG_SLOPE * sc;
        al[li][b] = lcnt[li] * __expf(sc - pv.x) * pv.y;
      }
    }
  }
  __syncthreads();
  float4 a0 = {0.f, 0.f, 0.f, 0.f}, a1 = {0.f, 0.f, 0.f, 0.f};
  for (int li = 0; li < len; ++li) {
    const int m = lme[li];
    const float4 v0 = *(const float4*)&out_e_t[(m * 64 + c) * 32 + bq * 8];
    const float4 v1 = *(const float4*)&out_e_t[(m * 64 + c) * 32 + bq * 8 + 4];
    const float* alr = al[li];
    a0.x = fmaf(alr[bq * 8 + 0], v0.x, a0.x);
    a0.y = fmaf(alr[bq * 8 + 1], v0.y, a0.y);
    a0.z = fmaf(alr[bq * 8 + 2], v0.z, a0.z);
    a0.w = fmaf(alr[bq * 8 + 3], v0.w, a0.w);
    a1.x = fmaf(alr[bq * 8 + 4], v1.x, a1.x);
    a1.y = fmaf(alr[bq * 8 + 5], v1.y, a1.y);
    a1.z = fmaf(alr[bq * 8 + 6], v1.z, a1.z);
    a1.w = fmaf(alr[bq * 8 + 7], v1.w, a1.w);
  }
  out[(bq * 8 + 0) * st + nb] = Dn * a0.x;
  out[(bq * 8 + 1) * st + nb] = Dn * a0.y;
  out[(bq * 8 + 2) * st + nb] = Dn * a0.z;
  out[(bq * 8 + 3) * st + nb] = Dn * a0.w;
  out[(bq * 8 + 4) * st + nb] = Dn * a1.x;
  out[(bq * 8 + 5) * st + nb] = Dn * a1.y;
  out[(bq * 8 + 6) * st + nb] = Dn * a1.z;
  out[(bq * 8 + 7) * st + nb] = Dn * a1.w;
}

extern "C" void kernel_launch(void* const* d_in, const int* in_sizes, int n_in,
                              void* d_out, int out_size, void* d_ws,
                              size_t ws_size, hipStream_t stream) {
  (void)in_sizes; (void)n_in; (void)out_size; (void)ws_size;
  const float* x = (const float*)d_in[0];
  const float* weight = (const float*)d_in[1];
  const float* att = (const float*)d_in[2];
  const int* node_ids = (const int*)d_in[3];
  float* out = (float*)d_out;

  char* wsb = (char*)d_ws;
  float* es_t = (float*)(wsb);                     // 512KB [m,c,b]
  float* out_e_t = (float*)(wsb + (512 << 10));    // 512KB [m,c,b]
  float* s1_t = (float*)(wsb + (1024 << 10));      // 512KB [n,b]
  int* cntv = (int*)(wsb + (1536 << 10));          // 1MB   [m,n]
  float2* pnb = (float2*)(wsb + (2560 << 10));     // 1MB   [n,b] {mx,invS}
  int* pdat = (int*)(wsb + (3584 << 10));          // 1MB   [n,64] packed m|cnt
  float* s2 = (float*)(wsb + (4608 << 10));        // 8KB
  float* nrm2 = (float*)(wsb + (4616 << 10));      // 8KB
  float* essum = (float*)(wsb + (4624 << 10));     // 8KB
  float* lossbuf2 = (float*)(wsb + (4632 << 10));  // 8KB (2016 floats)
  int* plen = (int*)(wsb + (4640 << 10));          // 16KB [n] len|Dsum<<7

  k_pA<<<1088, 256, 0, stream>>>(x, weight, att, node_ids, s1_t, es_t, s2,
                                 nrm2, essum, cntv);
  k_pB<<<1016, 256, 0, stream>>>(es_t, nrm2, cntv, s1_t, s2, lossbuf2, pnb,
                                 pdat, plen);
  k_pC<<<513, 256, 0, stream>>>(x, node_ids, weight, s1_t, s2, pnb, essum,
                                lossbuf2, out_e_t,
                                out + (size_t)B_SZ * N_NODES * C_DIM);
  k_pD<<<4096, 256, 0, stream>>>(plen, pdat, s1_t, s2, pnb, out_e_t, out);
}